// Round 4
// baseline (257.706 us; speedup 1.0000x reference)
//
#include <hip/hip_runtime.h>
#include <hip/hip_bf16.h>

#define N_NODES 10000
#define N_EDGES 640000
#define D 128

typedef unsigned int uint;
typedef unsigned short u16;

__device__ __forceinline__ u16 f2bf(float f) {
    uint u = __float_as_uint(f);
    uint r = (u + 0x7fffu + ((u >> 16) & 1u)) >> 16;   // round-to-nearest-even
    return (u16)r;
}
__device__ __forceinline__ float bf2f(u16 h) {
    return __uint_as_float(((uint)h) << 16);
}

// ---------------------------------------------------------------------------
// Edge-index dtype probe (int64 vs int32). flag=1 -> int32.
__global__ void detect_kernel(const void* ei, int* flag) {
    const int* p = (const int*)ei;
    bool nz = false;
    for (int it = 0; it < 16; ++it) {
        int i = 2 * (threadIdx.x + it * 256) + 1;   // odd words in [1, 8191]
        if (p[i] != 0) nz = true;
    }
    if (__any(nz) && (threadIdx.x & 63) == 0) flag[0] = 1;
}

__device__ __forceinline__ int edge_at(const void* ei, int is32, int idx) {
    if (is32) return ((const int*)ei)[idx];
    return (int)((const long long*)ei)[idx];
}

// ---------------------------------------------------------------------------
// int degree histogram over dst
__global__ void deg_kernel(const void* __restrict__ ei, const int* __restrict__ flag,
                           int* __restrict__ deg) {
    int e = blockIdx.x * 256 + threadIdx.x;
    if (e >= N_EDGES) return;
    int is32 = *flag;
    int dn = edge_at(ei, is32, N_EDGES + e);
    atomicAdd(&deg[dn], 1);
}

// ---------------------------------------------------------------------------
// exclusive prefix scan: row_start[i] = sum(deg[0..i-1]), row_start[N]=E
__global__ void scan_kernel(const int* __restrict__ deg, int* __restrict__ row_start) {
    __shared__ int lsum[256];
    __shared__ int lpre[257];
    int t = threadIdx.x;
    const int CH = 40;                     // 256*40 = 10240 >= N_NODES+1
    int base = t * CH;
    int s = 0;
    for (int k = 0; k < CH; ++k) { int i = base + k; if (i < N_NODES) s += deg[i]; }
    lsum[t] = s;
    __syncthreads();
    if (t == 0) {
        int c = 0;
        for (int u = 0; u < 256; ++u) { lpre[u] = c; c += lsum[u]; }
        lpre[256] = c;
    }
    __syncthreads();
    int run = lpre[t];
    for (int k = 0; k < CH; ++k) {
        int i = base + k;
        if (i <= N_NODES) {
            row_start[i] = run;
            if (i < N_NODES) run += deg[i];
        }
    }
}

// ---------------------------------------------------------------------------
// CSR fill: adj[row_start[dst] + cursor[dst]++] = (u16)src
__global__ void fill_kernel(const void* __restrict__ ei, const int* __restrict__ flag,
                            const int* __restrict__ row_start, int* __restrict__ cursor,
                            u16* __restrict__ adj) {
    int e = blockIdx.x * 256 + threadIdx.x;
    if (e >= N_EDGES) return;
    int is32 = *flag;
    int s  = edge_at(ei, is32, e);
    int dn = edge_at(ei, is32, N_EDGES + e);
    int pos = atomicAdd(&cursor[dn], 1);
    adj[row_start[dn] + pos] = (u16)s;
}

// ---------------------------------------------------------------------------
// f32 [N,D] -> bf16 [N,D]; 8 elems per thread
__global__ void cast_kernel(const float* __restrict__ in, uint* __restrict__ outb) {
    int t = blockIdx.x * 256 + threadIdx.x;
    if (t >= N_NODES * D / 8) return;
    const float4* p = (const float4*)in + (size_t)t * 2;
    float4 a = p[0], b = p[1];
    uint4 r;
    r.x = (uint)f2bf(a.x) | ((uint)f2bf(a.y) << 16);
    r.y = (uint)f2bf(a.z) | ((uint)f2bf(a.w) << 16);
    r.z = (uint)f2bf(b.x) | ((uint)f2bf(b.y) << 16);
    r.w = (uint)f2bf(b.z) | ((uint)f2bf(b.w) << 16);
    ((uint4*)outb)[t] = r;
}

// ---------------------------------------------------------------------------
// agg[i,:] = mean over neighbors j of xb[j,:] (bf16 in, f32 accumulate)
__global__ void gather_kernel(const u16* __restrict__ xb, const u16* __restrict__ adj,
                              const int* __restrict__ row_start, float* __restrict__ agg) {
    int i = blockIdx.x;
    int d = threadIdx.x;
    int beg = row_start[i], end = row_start[i + 1];
    float acc = 0.0f;
    int p = beg;
    for (; p + 4 <= end; p += 4) {
        int j0 = adj[p], j1 = adj[p + 1], j2 = adj[p + 2], j3 = adj[p + 3];
        float v0 = bf2f(xb[(size_t)j0 * D + d]);
        float v1 = bf2f(xb[(size_t)j1 * D + d]);
        float v2 = bf2f(xb[(size_t)j2 * D + d]);
        float v3 = bf2f(xb[(size_t)j3 * D + d]);
        acc += v0 + v1 + v2 + v3;
    }
    for (; p < end; ++p) acc += bf2f(xb[(size_t)adj[p] * D + d]);
    float cnt = (float)(end - beg);
    agg[(size_t)i * D + d] = acc / fmaxf(cnt, 1.0f);
}

// ---------------------------------------------------------------------------
// out[i,:] = ELU(agg[i,:] @ Wl + b + x[i,:] @ Wr)  — 32 nodes/block, 256 thr.
#define NT 32
__global__ __launch_bounds__(256)
void gemm_kernel(const float* __restrict__ x, const float* __restrict__ agg,
                 const float* __restrict__ Wl, const float* __restrict__ b,
                 const float* __restrict__ Wr, float* __restrict__ out) {
    __shared__ float as_[NT][D];
    __shared__ float xs_[NT][D];
    const int nb = blockIdx.x * NT;
    const int t  = threadIdx.x;

    float4*       asf4 = (float4*)&as_[0][0];
    float4*       xsf4 = (float4*)&xs_[0][0];
    const float4* af4  = (const float4*)(agg + (size_t)nb * D);
    const float4* xf4  = (const float4*)(x   + (size_t)nb * D);
    const int nvalid4 = (N_NODES - nb) * (D / 4);
#pragma unroll
    for (int q = 0; q < (NT * D / 4) / 256; ++q) {      // 4 iterations
        int idx = t + q * 256;
        float4 av = make_float4(0.f, 0.f, 0.f, 0.f), xv = av;
        if (idx < nvalid4) { av = af4[idx]; xv = xf4[idx]; }
        asf4[idx] = av;
        xsf4[idx] = xv;
    }
    __syncthreads();

    const int d = t & 127;          // output column
    const int h = t >> 7;           // node half: 0 or 1
    float acc[NT / 2];
#pragma unroll
    for (int n = 0; n < NT / 2; ++n) acc[n] = 0.0f;

    const float4* asq = (const float4*)&as_[h * (NT / 2)][0];
    const float4* xsq = (const float4*)&xs_[h * (NT / 2)][0];

    for (int k4 = 0; k4 < D / 4; ++k4) {
        float wl0 = Wl[(k4 * 4 + 0) * D + d];
        float wl1 = Wl[(k4 * 4 + 1) * D + d];
        float wl2 = Wl[(k4 * 4 + 2) * D + d];
        float wl3 = Wl[(k4 * 4 + 3) * D + d];
        float wr0 = Wr[(k4 * 4 + 0) * D + d];
        float wr1 = Wr[(k4 * 4 + 1) * D + d];
        float wr2 = Wr[(k4 * 4 + 2) * D + d];
        float wr3 = Wr[(k4 * 4 + 3) * D + d];
#pragma unroll
        for (int n = 0; n < NT / 2; ++n) {
            float4 a4 = asq[n * (D / 4) + k4];
            float4 x4 = xsq[n * (D / 4) + k4];
            acc[n] += a4.x * wl0 + a4.y * wl1 + a4.z * wl2 + a4.w * wl3
                    + x4.x * wr0 + x4.y * wr1 + x4.z * wr2 + x4.w * wr3;
        }
    }

    float bias = b[d];
#pragma unroll
    for (int n = 0; n < NT / 2; ++n) {
        int node = nb + h * (NT / 2) + n;
        if (node < N_NODES) {
            float v = acc[n] + bias;
            out[(size_t)node * D + d] = v > 0.0f ? v : expm1f(v);  // ELU alpha=1
        }
    }
}

// ---------------------------------------------------------------------------
extern "C" void kernel_launch(void* const* d_in, const int* in_sizes, int n_in,
                              void* d_out, int out_size, void* d_ws, size_t ws_size,
                              hipStream_t stream) {
    const float* x   = (const float*)d_in[0];
    const void*  ei  = d_in[1];
    const float* Wl0 = (const float*)d_in[2];
    const float* b0  = (const float*)d_in[3];
    const float* Wr0 = (const float*)d_in[4];
    const float* Wl1 = (const float*)d_in[5];
    const float* b1  = (const float*)d_in[6];
    const float* Wr1 = (const float*)d_in[7];
    float* out = (float*)d_out;

    char* ws = (char*)d_ws;
    int*   flag      = (int*)(ws + 0);
    int*   deg       = (int*)(ws + 1024);         // 40000 B
    int*   row_start = (int*)(ws + 65536);        // 40004 B
    int*   cursor    = (int*)(ws + 131072);       // 40000 B
    u16*   adj       = (u16*)(ws + 262144);       // 1.28 MB
    u16*   xb        = (u16*)(ws + 2097152);      // 2.56 MB bf16 copy
    float* agg       = (float*)(ws + 5242880);    // 5.12 MB

    // zero flag + deg + cursor (row_start/adj/xb/agg fully overwritten)
    hipMemsetAsync(ws, 0, 171072, stream);

    detect_kernel<<<1, 256, 0, stream>>>(ei, flag);
    deg_kernel<<<(N_EDGES + 255) / 256, 256, 0, stream>>>(ei, flag, deg);
    scan_kernel<<<1, 256, 0, stream>>>(deg, row_start);
    fill_kernel<<<(N_EDGES + 255) / 256, 256, 0, stream>>>(ei, flag, row_start, cursor, adj);

    const int cast_grid = (N_NODES * D / 8 + 255) / 256;   // 625
    const int gemm_grid = (N_NODES + NT - 1) / NT;         // 313

    // layer 0
    cast_kernel<<<cast_grid, 256, 0, stream>>>(x, (uint*)xb);
    gather_kernel<<<N_NODES, D, 0, stream>>>(xb, adj, row_start, agg);
    gemm_kernel<<<gemm_grid, 256, 0, stream>>>(x, agg, Wl0, b0, Wr0, out);

    // layer 1 (in place)
    cast_kernel<<<cast_grid, 256, 0, stream>>>(out, (uint*)xb);
    gather_kernel<<<N_NODES, D, 0, stream>>>(xb, adj, row_start, agg);
    gemm_kernel<<<gemm_grid, 256, 0, stream>>>(out, agg, Wl1, b1, Wr1, out);
}

// Round 5
// 170.710 us; speedup vs baseline: 1.5096x; 1.5096x over previous
//
#include <hip/hip_runtime.h>

#define N_NODES 10000
#define N_EDGES 640000
#define D 128
#define MAXDEG 128

typedef unsigned int uint;
typedef unsigned short u16;

__device__ __forceinline__ u16 f2bf(float f) {
    uint u = __float_as_uint(f);
    return (u16)((u + 0x7fffu + ((u >> 16) & 1u)) >> 16);   // round-nearest-even
}
__device__ __forceinline__ float bflo(uint v) { return __uint_as_float(v << 16); }
__device__ __forceinline__ float bfhi(uint v) { return __uint_as_float(v & 0xffff0000u); }

// ---------------------------------------------------------------------------
// Edge-index dtype probe (int64 vs int32). flag=1 -> int32.
__global__ void detect_kernel(const void* ei, int* flag) {
    const int* p = (const int*)ei;
    bool nz = false;
    for (int it = 0; it < 16; ++it) {
        int i = 2 * (threadIdx.x + it * 256) + 1;   // odd words in [1, 8191]
        if (p[i] != 0) nz = true;
    }
    if (__any(nz) && (threadIdx.x & 63) == 0) flag[0] = 1;
}

__device__ __forceinline__ int edge_at(const void* ei, int is32, int idx) {
    if (is32) return ((const int*)ei)[idx];
    return (int)((const long long*)ei)[idx];
}

// ---------------------------------------------------------------------------
// One-pass padded-CSR fill, XCD-sliced by dst range:
//   block b handles dst in slice (b&7); blockIdx%8 maps to XCD (round-robin
//   heuristic) so adj/cursor lines stay XCD-local. cursor ends up = degree.
__global__ __launch_bounds__(256)
void fill_kernel(const void* __restrict__ ei, const int* __restrict__ flag,
                 int* __restrict__ cursor, u16* __restrict__ adj) {
    const int xcd  = blockIdx.x & 7;
    const int blk  = blockIdx.x >> 3;
    const int nblk = gridDim.x >> 3;
    const int lo = xcd * (N_NODES / 8);
    const int hi = lo + (N_NODES / 8);
    const int is32 = *flag;
    for (int e = blk * 256 + threadIdx.x; e < N_EDGES; e += nblk * 256) {
        int dn = edge_at(ei, is32, N_EDGES + e);
        if (dn >= lo && dn < hi) {
            int s = edge_at(ei, is32, e);
            int pos = atomicAdd(&cursor[dn], 1);
            if (pos < MAXDEG) adj[(size_t)dn * MAXDEG + pos] = (u16)s;
        }
    }
}

// ---------------------------------------------------------------------------
// f32 [N,D] -> packed bf16x2 [N,D/2]; 8 elems per thread
__global__ void cast_kernel(const float* __restrict__ in, uint* __restrict__ outb) {
    int t = blockIdx.x * 256 + threadIdx.x;
    if (t >= N_NODES * D / 8) return;
    const float4* p = (const float4*)in + (size_t)t * 2;
    float4 a = p[0], b = p[1];
    uint4 r;
    r.x = (uint)f2bf(a.x) | ((uint)f2bf(a.y) << 16);
    r.y = (uint)f2bf(a.z) | ((uint)f2bf(a.w) << 16);
    r.z = (uint)f2bf(b.x) | ((uint)f2bf(b.y) << 16);
    r.w = (uint)f2bf(b.z) | ((uint)f2bf(b.w) << 16);
    ((uint4*)outb)[t] = r;
}

// ---------------------------------------------------------------------------
// aggb[i,:] = mean over neighbors (bf16 in, f32 accum, bf16 out).
// One wave per node; lane c owns cols 2c,2c+1 (one packed uint).
__global__ __launch_bounds__(256)
void gather_kernel(const uint* __restrict__ xb2, const u16* __restrict__ adj,
                   const int* __restrict__ cursor, uint* __restrict__ aggb2) {
    const int node = blockIdx.x * 4 + (threadIdx.x >> 6);
    const int c = threadIdx.x & 63;
    const int deg = cursor[node];
    const int cnt = min(deg, MAXDEG);
    const uint* __restrict__ rowu = (const uint*)(adj + (size_t)node * MAXDEG);
    float a0 = 0.f, a1 = 0.f;
    int p = 0;
    for (; p + 8 <= cnt; p += 8) {
        uint pk0 = rowu[(p >> 1) + 0];
        uint pk1 = rowu[(p >> 1) + 1];
        uint pk2 = rowu[(p >> 1) + 2];
        uint pk3 = rowu[(p >> 1) + 3];
        uint v0 = xb2[(size_t)(pk0 & 0xffffu) * 64 + c];
        uint v1 = xb2[(size_t)(pk0 >> 16)     * 64 + c];
        uint v2 = xb2[(size_t)(pk1 & 0xffffu) * 64 + c];
        uint v3 = xb2[(size_t)(pk1 >> 16)     * 64 + c];
        uint v4 = xb2[(size_t)(pk2 & 0xffffu) * 64 + c];
        uint v5 = xb2[(size_t)(pk2 >> 16)     * 64 + c];
        uint v6 = xb2[(size_t)(pk3 & 0xffffu) * 64 + c];
        uint v7 = xb2[(size_t)(pk3 >> 16)     * 64 + c];
        a0 += bflo(v0) + bflo(v1) + bflo(v2) + bflo(v3)
            + bflo(v4) + bflo(v5) + bflo(v6) + bflo(v7);
        a1 += bfhi(v0) + bfhi(v1) + bfhi(v2) + bfhi(v3)
            + bfhi(v4) + bfhi(v5) + bfhi(v6) + bfhi(v7);
    }
    for (; p < cnt; ++p) {
        int j = ((const u16*)rowu)[p];
        uint v = xb2[(size_t)j * 64 + c];
        a0 += bflo(v);
        a1 += bfhi(v);
    }
    float inv = 1.0f / fmaxf((float)deg, 1.0f);
    aggb2[(size_t)node * 64 + c] = (uint)f2bf(a0 * inv) | ((uint)f2bf(a1 * inv) << 16);
}

// ---------------------------------------------------------------------------
// out[i,:] = ELU(agg[i,:] @ Wl + b + x[i,:] @ Wr); optionally also bf16 copy.
// 16 nodes/block, 128 threads (thread = output column), acc[16]/thread.
#define NT 16
__global__ __launch_bounds__(128)
void gemm_kernel(const float* __restrict__ xin, const uint* __restrict__ aggb2,
                 const float* __restrict__ Wl, const float* __restrict__ bias,
                 const float* __restrict__ Wr, float* __restrict__ out,
                 u16* __restrict__ outb /* may be null */) {
    __shared__ float as_[NT][D];
    __shared__ float xs_[NT][D];
    const int nb = blockIdx.x * NT;          // 625*16 == 10000, no tail
    const int t  = threadIdx.x;

    {
        const uint* src = aggb2 + (size_t)nb * 64;
        float* dst = &as_[0][0];
#pragma unroll
        for (int q = 0; q < 8; ++q) {
            int idx = t + q * 128;           // 0..1023 packed uints
            uint v = src[idx];
            dst[idx * 2]     = bflo(v);
            dst[idx * 2 + 1] = bfhi(v);
        }
        const float4* xsrc = (const float4*)(xin + (size_t)nb * D);
        float4* xdst = (float4*)&xs_[0][0];
#pragma unroll
        for (int q = 0; q < 4; ++q) xdst[t + q * 128] = xsrc[t + q * 128];
    }
    __syncthreads();

    const int d = t;
    float acc[NT];
#pragma unroll
    for (int n = 0; n < NT; ++n) acc[n] = 0.f;

    const float4* as4 = (const float4*)&as_[0][0];   // [NT][32]
    const float4* xs4 = (const float4*)&xs_[0][0];

    for (int k4 = 0; k4 < D / 4; ++k4) {
        float wl0 = Wl[(k4 * 4 + 0) * D + d];
        float wl1 = Wl[(k4 * 4 + 1) * D + d];
        float wl2 = Wl[(k4 * 4 + 2) * D + d];
        float wl3 = Wl[(k4 * 4 + 3) * D + d];
        float wr0 = Wr[(k4 * 4 + 0) * D + d];
        float wr1 = Wr[(k4 * 4 + 1) * D + d];
        float wr2 = Wr[(k4 * 4 + 2) * D + d];
        float wr3 = Wr[(k4 * 4 + 3) * D + d];
#pragma unroll
        for (int n = 0; n < NT; ++n) {
            float4 a4 = as4[n * 32 + k4];    // wave-uniform addr -> LDS broadcast
            float4 x4 = xs4[n * 32 + k4];
            acc[n] += a4.x * wl0 + a4.y * wl1 + a4.z * wl2 + a4.w * wl3
                    + x4.x * wr0 + x4.y * wr1 + x4.z * wr2 + x4.w * wr3;
        }
    }

    float bv = bias[d];
#pragma unroll
    for (int n = 0; n < NT; ++n) {
        float v = acc[n] + bv;
        v = v > 0.f ? v : expm1f(v);         // ELU alpha=1
        out[(size_t)(nb + n) * D + d] = v;
        acc[n] = v;
    }
    if (outb) {
#pragma unroll
        for (int n = 0; n < NT; ++n) outb[(size_t)(nb + n) * D + d] = f2bf(acc[n]);
    }
}

// ---------------------------------------------------------------------------
extern "C" void kernel_launch(void* const* d_in, const int* in_sizes, int n_in,
                              void* d_out, int out_size, void* d_ws, size_t ws_size,
                              hipStream_t stream) {
    const float* x   = (const float*)d_in[0];
    const void*  ei  = d_in[1];
    const float* Wl0 = (const float*)d_in[2];
    const float* b0  = (const float*)d_in[3];
    const float* Wr0 = (const float*)d_in[4];
    const float* Wl1 = (const float*)d_in[5];
    const float* b1  = (const float*)d_in[6];
    const float* Wr1 = (const float*)d_in[7];
    float* out = (float*)d_out;

    char* ws = (char*)d_ws;
    int*  flag   = (int*)(ws + 0);
    int*  cursor = (int*)(ws + 1024);            // 40000 B, also final degree
    u16*  adj    = (u16*)(ws + 65536);           // 10000*128*2 = 2.56 MB
    uint* xb2    = (uint*)(ws + 3145728);        // 2.56 MB packed bf16
    uint* aggb2  = (uint*)(ws + 6291456);        // 2.56 MB packed bf16

    hipMemsetAsync(ws, 0, 48 * 1024, stream);    // flag + cursor

    detect_kernel<<<1, 256, 0, stream>>>(ei, flag);
    fill_kernel<<<2048, 256, 0, stream>>>(ei, flag, cursor, adj);
    cast_kernel<<<625, 256, 0, stream>>>(x, xb2);            // N*D/8/256

    // layer 0: gemm also emits bf16 activations into xb2 for layer-1 gather
    gather_kernel<<<2500, 256, 0, stream>>>(xb2, adj, cursor, aggb2);
    gemm_kernel<<<625, 128, 0, stream>>>(x, aggb2, Wl0, b0, Wr0, out, (u16*)xb2);

    // layer 1 (in place on out)
    gather_kernel<<<2500, 256, 0, stream>>>(xb2, adj, cursor, aggb2);
    gemm_kernel<<<625, 128, 0, stream>>>(out, aggb2, Wl1, b1, Wr1, out, (u16*)0);
}

// Round 6
// 136.422 us; speedup vs baseline: 1.8890x; 1.2513x over previous
//
#include <hip/hip_runtime.h>

#define N_NODES 10000
#define N_EDGES 640000
#define D 128
#define MAXDEG 128
#define NBUCK 157            // ceil(10000 / 64) buckets of 64 dst nodes
#define BCAP 6144            // bucket capacity; mean 4076, sigma ~64 -> +32 sigma
#define EPT 10               // edges/thread in pass1: 250 blocks * 256 * 10 = 640000

typedef unsigned int uint;
typedef unsigned short u16;

__device__ __forceinline__ u16 f2bf(float f) {
    uint u = __float_as_uint(f);
    return (u16)((u + 0x7fffu + ((u >> 16) & 1u)) >> 16);   // round-nearest-even
}
__device__ __forceinline__ float bflo(uint v) { return __uint_as_float(v << 16); }
__device__ __forceinline__ float bfhi(uint v) { return __uint_as_float(v & 0xffff0000u); }

// ---------------------------------------------------------------------------
// Edge-index dtype probe (int64 vs int32). flag=1 -> int32.
__global__ void detect_kernel(const void* ei, int* flag) {
    const int* p = (const int*)ei;
    bool nz = false;
    for (int it = 0; it < 16; ++it) {
        int i = 2 * (threadIdx.x + it * 256) + 1;   // odd words in [1, 8191]
        if (p[i] != 0) nz = true;
    }
    if (__any(nz) && (threadIdx.x & 63) == 0) flag[0] = 1;
}

__device__ __forceinline__ int edge_at(const void* ei, int is32, int idx) {
    if (is32) return ((const int*)ei)[idx];
    return (int)((const long long*)ei)[idx];
}

// ---------------------------------------------------------------------------
// Pass 1: bin packed (dst<<16 | src) edges into NBUCK global bucket arrays.
// LDS histogram assigns per-edge ranks; one global atomicAdd per (block,bucket).
__global__ __launch_bounds__(256)
void binp1_kernel(const void* __restrict__ ei, const int* __restrict__ flag,
                  int* __restrict__ gcount, uint* __restrict__ gbucket) {
    __shared__ int hist[NBUCK];
    __shared__ int base[NBUCK];
    const int t = threadIdx.x;
    if (t < NBUCK) hist[t] = 0;
    __syncthreads();
    const int is32 = *flag;
    const int e0 = blockIdx.x * (256 * EPT);
    uint pk[EPT];
    int  rk[EPT];
#pragma unroll
    for (int i = 0; i < EPT; ++i) {
        int e  = e0 + i * 256 + t;
        int s  = edge_at(ei, is32, e);
        int dn = edge_at(ei, is32, N_EDGES + e);
        pk[i] = ((uint)dn << 16) | (uint)s;
        rk[i] = atomicAdd(&hist[dn >> 6], 1);
    }
    __syncthreads();
    if (t < NBUCK) base[t] = atomicAdd(&gcount[t], hist[t]);
    __syncthreads();
#pragma unroll
    for (int i = 0; i < EPT; ++i) {
        int bkt = (int)(pk[i] >> 22);
        int pos = base[bkt] + rk[i];
        if (pos < BCAP) gbucket[(size_t)bkt * BCAP + pos] = pk[i];
    }
}

// ---------------------------------------------------------------------------
// Pass 2: one block per bucket; counting-sort edges into a 64x128 u16 LDS tile,
// then write adj rows coalesced (uint4) + per-node degree.
__global__ __launch_bounds__(256)
void binp2_kernel(const int* __restrict__ gcount, const uint* __restrict__ gbucket,
                  u16* __restrict__ adj, int* __restrict__ deg_g) {
    __shared__ __align__(16) u16 tile[64][MAXDEG];   // 16 KB
    __shared__ int cur[64];
    const int b = blockIdx.x;
    const int t = threadIdx.x;
    if (t < 64) cur[t] = 0;
    __syncthreads();
    const int total = min(gcount[b], BCAP);
    for (int e = t; e < total; e += 256) {
        uint pk = gbucket[(size_t)b * BCAP + e];
        int ln  = (int)((pk >> 16) & 63u);
        int src = (int)(pk & 0xffffu);
        int r = atomicAdd(&cur[ln], 1);
        if (r < MAXDEG) tile[ln][r] = (u16)src;
    }
    __syncthreads();
    const int node0 = b * 64;
    if (t < 64 && node0 + t < N_NODES) deg_g[node0 + t] = cur[t];
    const uint4* ts = (const uint4*)&tile[0][0];     // 1024 uint4, 16 per row
#pragma unroll
    for (int q = 0; q < 4; ++q) {
        int i = t + q * 256;
        int node = node0 + (i >> 4);
        if (node < N_NODES) ((uint4*)(adj + (size_t)node * MAXDEG))[i & 15] = ts[i];
    }
}

// ---------------------------------------------------------------------------
// f32 [N,D] -> packed bf16x2 [N,D/2]; 8 elems per thread
__global__ void cast_kernel(const float* __restrict__ in, uint* __restrict__ outb) {
    int t = blockIdx.x * 256 + threadIdx.x;
    if (t >= N_NODES * D / 8) return;
    const float4* p = (const float4*)in + (size_t)t * 2;
    float4 a = p[0], b = p[1];
    uint4 r;
    r.x = (uint)f2bf(a.x) | ((uint)f2bf(a.y) << 16);
    r.y = (uint)f2bf(a.z) | ((uint)f2bf(a.w) << 16);
    r.z = (uint)f2bf(b.x) | ((uint)f2bf(b.y) << 16);
    r.w = (uint)f2bf(b.z) | ((uint)f2bf(b.w) << 16);
    ((uint4*)outb)[t] = r;
}

// ---------------------------------------------------------------------------
// Fused layer: gather mean into LDS (bf16 src, f32 accum) then
// out[i,:] = ELU(agg@Wl + b + x@Wr). 16 nodes/block, 256 threads.
// Gather: wave w handles nodes w*4..w*4+3; lane c owns packed col c (2 cols).
// Gemm: d = t&127 output column, h = t>>7 node half, acc[8].
__global__ __launch_bounds__(256)
void fused_kernel(const float* __restrict__ xin, const uint* __restrict__ gsrc,
                  const u16* __restrict__ adj, const int* __restrict__ deg_g,
                  const float* __restrict__ Wl, const float* __restrict__ bias,
                  const float* __restrict__ Wr, float* __restrict__ out,
                  u16* __restrict__ outb /* may be null */) {
    __shared__ float as_[16][D];
    __shared__ float xs_[16][D];
    const int nb = blockIdx.x * 16;
    const int t = threadIdx.x;
    const int wave = t >> 6, lane = t & 63;

    for (int q = 0; q < 4; ++q) {
        const int li = wave * 4 + q;
        const int node = nb + li;
        const int dg = deg_g[node];
        const int cnt = min(dg, MAXDEG);
        const uint* __restrict__ rowu = (const uint*)(adj + (size_t)node * MAXDEG);
        float a0 = 0.f, a1 = 0.f;
        int p = 0;
        for (; p + 8 <= cnt; p += 8) {
            uint pk0 = rowu[(p >> 1) + 0];
            uint pk1 = rowu[(p >> 1) + 1];
            uint pk2 = rowu[(p >> 1) + 2];
            uint pk3 = rowu[(p >> 1) + 3];
            uint v0 = gsrc[(size_t)(pk0 & 0xffffu) * 64 + lane];
            uint v1 = gsrc[(size_t)(pk0 >> 16)     * 64 + lane];
            uint v2 = gsrc[(size_t)(pk1 & 0xffffu) * 64 + lane];
            uint v3 = gsrc[(size_t)(pk1 >> 16)     * 64 + lane];
            uint v4 = gsrc[(size_t)(pk2 & 0xffffu) * 64 + lane];
            uint v5 = gsrc[(size_t)(pk2 >> 16)     * 64 + lane];
            uint v6 = gsrc[(size_t)(pk3 & 0xffffu) * 64 + lane];
            uint v7 = gsrc[(size_t)(pk3 >> 16)     * 64 + lane];
            a0 += bflo(v0) + bflo(v1) + bflo(v2) + bflo(v3)
                + bflo(v4) + bflo(v5) + bflo(v6) + bflo(v7);
            a1 += bfhi(v0) + bfhi(v1) + bfhi(v2) + bfhi(v3)
                + bfhi(v4) + bfhi(v5) + bfhi(v6) + bfhi(v7);
        }
        for (; p < cnt; ++p) {
            int j = ((const u16*)rowu)[p];
            uint v = gsrc[(size_t)j * 64 + lane];
            a0 += bflo(v);
            a1 += bfhi(v);
        }
        float inv = 1.0f / fmaxf((float)dg, 1.0f);
        as_[li][lane * 2]     = a0 * inv;
        as_[li][lane * 2 + 1] = a1 * inv;
    }
    {
        const float4* xsrc = (const float4*)(xin + (size_t)nb * D);
        float4* xdst = (float4*)&xs_[0][0];
        xdst[t]       = xsrc[t];
        xdst[t + 256] = xsrc[t + 256];
    }
    __syncthreads();

    const int d = t & 127;
    const int h = t >> 7;
    float acc[8];
#pragma unroll
    for (int n = 0; n < 8; ++n) acc[n] = 0.f;

    const float4* as4 = (const float4*)&as_[h * 8][0];
    const float4* xs4 = (const float4*)&xs_[h * 8][0];

    for (int k4 = 0; k4 < D / 4; ++k4) {
        float wl0 = Wl[(k4 * 4 + 0) * D + d];
        float wl1 = Wl[(k4 * 4 + 1) * D + d];
        float wl2 = Wl[(k4 * 4 + 2) * D + d];
        float wl3 = Wl[(k4 * 4 + 3) * D + d];
        float wr0 = Wr[(k4 * 4 + 0) * D + d];
        float wr1 = Wr[(k4 * 4 + 1) * D + d];
        float wr2 = Wr[(k4 * 4 + 2) * D + d];
        float wr3 = Wr[(k4 * 4 + 3) * D + d];
#pragma unroll
        for (int n = 0; n < 8; ++n) {
            float4 a4 = as4[n * 32 + k4];
            float4 x4 = xs4[n * 32 + k4];
            acc[n] += a4.x * wl0 + a4.y * wl1 + a4.z * wl2 + a4.w * wl3
                    + x4.x * wr0 + x4.y * wr1 + x4.z * wr2 + x4.w * wr3;
        }
    }

    float bv = bias[d];
#pragma unroll
    for (int n = 0; n < 8; ++n) {
        float v = acc[n] + bv;
        v = v > 0.f ? v : expm1f(v);                 // ELU alpha=1
        int node = nb + h * 8 + n;
        out[(size_t)node * D + d] = v;
        if (outb) outb[(size_t)node * D + d] = f2bf(v);
    }
}

// ---------------------------------------------------------------------------
extern "C" void kernel_launch(void* const* d_in, const int* in_sizes, int n_in,
                              void* d_out, int out_size, void* d_ws, size_t ws_size,
                              hipStream_t stream) {
    const float* x   = (const float*)d_in[0];
    const void*  ei  = d_in[1];
    const float* Wl0 = (const float*)d_in[2];
    const float* b0  = (const float*)d_in[3];
    const float* Wr0 = (const float*)d_in[4];
    const float* Wl1 = (const float*)d_in[5];
    const float* b1  = (const float*)d_in[6];
    const float* Wr1 = (const float*)d_in[7];
    float* out = (float*)d_out;

    char* ws = (char*)d_ws;
    // lifetime: gbucket dies after binp2; xb2/yb2 overlay its region.
    int*  flag    = (int*)(ws + 0);
    int*  gcount  = (int*)(ws + 1024);           // 628 B
    int*  deg     = (int*)(ws + 4096);           // 40 KB
    u16*  adj     = (u16*)(ws + 65536);          // 2.56 MB -> ends 2,625,536
    uint* gbucket = (uint*)(ws + 3145728);       // 3.86 MB -> ends 7,004,160
    uint* xb2     = (uint*)(ws + 3145728);       // 2.56 MB (after binp2)
    uint* yb2     = (uint*)(ws + 5767168);       // 2.56 MB -> ends 8,327,168

    hipMemsetAsync(ws, 0, 2048, stream);         // flag + gcount

    detect_kernel<<<1, 256, 0, stream>>>(ei, flag);
    binp1_kernel<<<250, 256, 0, stream>>>(ei, flag, gcount, gbucket);
    binp2_kernel<<<NBUCK, 256, 0, stream>>>(gcount, gbucket, adj, deg);
    cast_kernel<<<625, 256, 0, stream>>>(x, xb2);

    // layer 0: gathers from xb2, emits f32 out + bf16 copy into yb2
    fused_kernel<<<625, 256, 0, stream>>>(x, xb2, adj, deg, Wl0, b0, Wr0, out, (u16*)yb2);
    // layer 1: gathers from yb2, in-place on out
    fused_kernel<<<625, 256, 0, stream>>>(out, yb2, adj, deg, Wl1, b1, Wr1, out, (u16*)0);
}

// Round 7
// 120.608 us; speedup vs baseline: 2.1367x; 1.1311x over previous
//
#include <hip/hip_runtime.h>

#define N_NODES 10000
#define N_EDGES 640000
#define D 128
#define MAXDEG 128
#define NBUCK 157            // ceil(10000 / 64) buckets of 64 dst nodes
#define BCAP 6144            // bucket capacity; mean 4076 -> huge margin
#define EPT 10               // edges/thread in pass1: 250 blocks * 256 * 10 = 640000

typedef unsigned int uint;
typedef unsigned short u16;

__device__ __forceinline__ u16 f2bf(float f) {
    uint u = __float_as_uint(f);
    return (u16)((u + 0x7fffu + ((u >> 16) & 1u)) >> 16);   // round-nearest-even
}
__device__ __forceinline__ float bflo(uint v) { return __uint_as_float(v << 16); }
__device__ __forceinline__ float bfhi(uint v) { return __uint_as_float(v & 0xffff0000u); }

// ---------------------------------------------------------------------------
// Edge-index dtype probe (int64 vs int32). flag=1 -> int32.
__global__ void detect_kernel(const void* ei, int* flag) {
    const int* p = (const int*)ei;
    bool nz = false;
    for (int it = 0; it < 16; ++it) {
        int i = 2 * (threadIdx.x + it * 256) + 1;   // odd words in [1, 8191]
        if (p[i] != 0) nz = true;
    }
    if (__any(nz) && (threadIdx.x & 63) == 0) flag[0] = 1;
}

__device__ __forceinline__ int edge_at(const void* ei, int is32, int idx) {
    if (is32) return ((const int*)ei)[idx];
    return (int)((const long long*)ei)[idx];
}

// ---------------------------------------------------------------------------
// Pass 1: bin packed (dst<<16 | src) edges into NBUCK global bucket arrays.
__global__ __launch_bounds__(256)
void binp1_kernel(const void* __restrict__ ei, const int* __restrict__ flag,
                  int* __restrict__ gcount, uint* __restrict__ gbucket) {
    __shared__ int hist[NBUCK];
    __shared__ int base[NBUCK];
    const int t = threadIdx.x;
    if (t < NBUCK) hist[t] = 0;
    __syncthreads();
    const int is32 = *flag;
    const int e0 = blockIdx.x * (256 * EPT);
    uint pk[EPT];
    int  rk[EPT];
#pragma unroll
    for (int i = 0; i < EPT; ++i) {
        int e  = e0 + i * 256 + t;
        int s  = edge_at(ei, is32, e);
        int dn = edge_at(ei, is32, N_EDGES + e);
        pk[i] = ((uint)dn << 16) | (uint)s;
        rk[i] = atomicAdd(&hist[dn >> 6], 1);
    }
    __syncthreads();
    if (t < NBUCK) base[t] = atomicAdd(&gcount[t], hist[t]);
    __syncthreads();
#pragma unroll
    for (int i = 0; i < EPT; ++i) {
        int bkt = (int)(pk[i] >> 22);
        int pos = base[bkt] + rk[i];
        if (pos < BCAP) gbucket[(size_t)bkt * BCAP + pos] = pk[i];
    }
}

// ---------------------------------------------------------------------------
// Pass 2: one block per bucket; counting-sort into 64x128 u16 LDS tile,
// write adj rows coalesced (uint4) + per-node degree.
__global__ __launch_bounds__(256)
void binp2_kernel(const int* __restrict__ gcount, const uint* __restrict__ gbucket,
                  u16* __restrict__ adj, int* __restrict__ deg_g) {
    __shared__ __align__(16) u16 tile[64][MAXDEG];   // 16 KB
    __shared__ int cur[64];
    const int b = blockIdx.x;
    const int t = threadIdx.x;
    if (t < 64) cur[t] = 0;
    __syncthreads();
    const int total = min(gcount[b], BCAP);
    for (int e = t; e < total; e += 256) {
        uint pk = gbucket[(size_t)b * BCAP + e];
        int ln  = (int)((pk >> 16) & 63u);
        int src = (int)(pk & 0xffffu);
        int r = atomicAdd(&cur[ln], 1);
        if (r < MAXDEG) tile[ln][r] = (u16)src;
    }
    __syncthreads();
    const int node0 = b * 64;
    if (t < 64 && node0 + t < N_NODES) deg_g[node0 + t] = cur[t];
    const uint4* ts = (const uint4*)&tile[0][0];     // 1024 uint4, 16 per row
#pragma unroll
    for (int q = 0; q < 4; ++q) {
        int i = t + q * 256;
        int node = node0 + (i >> 4);
        if (node < N_NODES) ((uint4*)(adj + (size_t)node * MAXDEG))[i & 15] = ts[i];
    }
}

// ---------------------------------------------------------------------------
// f32 [N,D] -> packed bf16x2 [N,D/2]; 8 elems per thread
__global__ void cast_kernel(const float* __restrict__ in, uint* __restrict__ outb) {
    int t = blockIdx.x * 256 + threadIdx.x;
    if (t >= N_NODES * D / 8) return;
    const float4* p = (const float4*)in + (size_t)t * 2;
    float4 a = p[0], b = p[1];
    uint4 r;
    r.x = (uint)f2bf(a.x) | ((uint)f2bf(a.y) << 16);
    r.y = (uint)f2bf(a.z) | ((uint)f2bf(a.w) << 16);
    r.z = (uint)f2bf(b.x) | ((uint)f2bf(b.y) << 16);
    r.w = (uint)f2bf(b.z) | ((uint)f2bf(b.w) << 16);
    ((uint4*)outb)[t] = r;
}

// ---------------------------------------------------------------------------
// Gather: one WAVE per node, full-occupancy grid (2500 blocks x 4 waves).
// 16-neighbor batches; next batch's adj words prefetched; all 16 gather
// loads issued into a register array before accumulation (16-24 in flight).
__global__ __launch_bounds__(256)
void gather_kernel(const uint* __restrict__ xb2, const u16* __restrict__ adj,
                   const int* __restrict__ deg_g, uint* __restrict__ aggb2) {
    const int node = blockIdx.x * 4 + (threadIdx.x >> 6);
    const int lane = threadIdx.x & 63;
    const int dg = deg_g[node];
    const int cnt = min(dg, MAXDEG);
    const uint* __restrict__ rowu = (const uint*)(adj + (size_t)node * MAXDEG);
    float a0 = 0.f, a1 = 0.f;
    const int nb16 = cnt >> 4;                 // full 16-neighbor batches
    if (nb16 > 0) {
        uint pkb[8];
#pragma unroll
        for (int i = 0; i < 8; ++i) pkb[i] = rowu[i];
        for (int b = 0; b < nb16; ++b) {
            uint cur[8];
#pragma unroll
            for (int i = 0; i < 8; ++i) cur[i] = pkb[i];
            if (b + 1 < nb16) {
#pragma unroll
                for (int i = 0; i < 8; ++i) pkb[i] = rowu[(b + 1) * 8 + i];
            }
            uint v[16];
#pragma unroll
            for (int i = 0; i < 8; ++i) {
                v[2 * i]     = xb2[(size_t)(cur[i] & 0xffffu) * 64 + lane];
                v[2 * i + 1] = xb2[(size_t)(cur[i] >> 16)     * 64 + lane];
            }
#pragma unroll
            for (int i = 0; i < 16; ++i) { a0 += bflo(v[i]); a1 += bfhi(v[i]); }
        }
    }
    for (int p = nb16 << 4; p < cnt; ++p) {
        uint v = xb2[(size_t)((const u16*)rowu)[p] * 64 + lane];
        a0 += bflo(v);
        a1 += bfhi(v);
    }
    float inv = 1.0f / fmaxf((float)dg, 1.0f);
    aggb2[(size_t)node * 64 + lane] = (uint)f2bf(a0 * inv) | ((uint)f2bf(a1 * inv) << 16);
}

// ---------------------------------------------------------------------------
// out[i,:] = ELU(agg[i,:] @ Wl + b + x[i,:] @ Wr); optional bf16 copy out.
// 16 nodes/block, 256 threads; d = t&127 output col, h = t>>7 node half.
__global__ __launch_bounds__(256)
void gemm_kernel(const float* __restrict__ xin, const uint* __restrict__ aggb2,
                 const float* __restrict__ Wl, const float* __restrict__ bias,
                 const float* __restrict__ Wr, float* __restrict__ out,
                 u16* __restrict__ outb /* may be null */) {
    __shared__ float as_[16][D];
    __shared__ float xs_[16][D];
    const int nb = blockIdx.x * 16;
    const int t = threadIdx.x;

    {
        const uint* src = aggb2 + (size_t)nb * 64;
        float* dst = &as_[0][0];
#pragma unroll
        for (int q = 0; q < 4; ++q) {
            int idx = t + q * 256;            // 0..1023 packed uints
            uint v = src[idx];
            dst[idx * 2]     = bflo(v);
            dst[idx * 2 + 1] = bfhi(v);
        }
        const float4* xsrc = (const float4*)(xin + (size_t)nb * D);
        float4* xdst = (float4*)&xs_[0][0];
        xdst[t]       = xsrc[t];
        xdst[t + 256] = xsrc[t + 256];
    }
    __syncthreads();

    const int d = t & 127;
    const int h = t >> 7;
    float acc[8];
#pragma unroll
    for (int n = 0; n < 8; ++n) acc[n] = 0.f;

    const float4* as4 = (const float4*)&as_[h * 8][0];
    const float4* xs4 = (const float4*)&xs_[h * 8][0];

    for (int k4 = 0; k4 < D / 4; ++k4) {
        float wl0 = Wl[(k4 * 4 + 0) * D + d];
        float wl1 = Wl[(k4 * 4 + 1) * D + d];
        float wl2 = Wl[(k4 * 4 + 2) * D + d];
        float wl3 = Wl[(k4 * 4 + 3) * D + d];
        float wr0 = Wr[(k4 * 4 + 0) * D + d];
        float wr1 = Wr[(k4 * 4 + 1) * D + d];
        float wr2 = Wr[(k4 * 4 + 2) * D + d];
        float wr3 = Wr[(k4 * 4 + 3) * D + d];
#pragma unroll
        for (int n = 0; n < 8; ++n) {
            float4 a4 = as4[n * 32 + k4];
            float4 x4 = xs4[n * 32 + k4];
            acc[n] += a4.x * wl0 + a4.y * wl1 + a4.z * wl2 + a4.w * wl3
                    + x4.x * wr0 + x4.y * wr1 + x4.z * wr2 + x4.w * wr3;
        }
    }

    float bv = bias[d];
#pragma unroll
    for (int n = 0; n < 8; ++n) {
        float v = acc[n] + bv;
        v = v > 0.f ? v : expm1f(v);                 // ELU alpha=1
        int node = nb + h * 8 + n;
        out[(size_t)node * D + d] = v;
        if (outb) outb[(size_t)node * D + d] = f2bf(v);
    }
}

// ---------------------------------------------------------------------------
extern "C" void kernel_launch(void* const* d_in, const int* in_sizes, int n_in,
                              void* d_out, int out_size, void* d_ws, size_t ws_size,
                              hipStream_t stream) {
    const float* x   = (const float*)d_in[0];
    const void*  ei  = d_in[1];
    const float* Wl0 = (const float*)d_in[2];
    const float* b0  = (const float*)d_in[3];
    const float* Wr0 = (const float*)d_in[4];
    const float* Wl1 = (const float*)d_in[5];
    const float* b1  = (const float*)d_in[6];
    const float* Wr1 = (const float*)d_in[7];
    float* out = (float*)d_out;

    char* ws = (char*)d_ws;
    // lifetime: gbucket dies after binp2; xb2 overlays its region.
    int*  flag    = (int*)(ws + 0);
    int*  gcount  = (int*)(ws + 1024);           // 628 B
    int*  deg     = (int*)(ws + 4096);           // 40 KB
    u16*  adj     = (u16*)(ws + 65536);          // 2.56 MB -> ends 2,625,536
    uint* gbucket = (uint*)(ws + 3145728);       // 3.86 MB -> ends 7,004,160
    uint* xb2     = (uint*)(ws + 3145728);       // 2.56 MB (after binp2)
    uint* yb2     = (uint*)(ws + 5767168);       // 2.56 MB -> ends 8,327,168
    uint* aggb2   = (uint*)(ws + 8388608);       // 2.56 MB -> ends 10,948,608

    hipMemsetAsync(ws, 0, 2048, stream);         // flag + gcount

    detect_kernel<<<1, 256, 0, stream>>>(ei, flag);
    binp1_kernel<<<250, 256, 0, stream>>>(ei, flag, gcount, gbucket);
    binp2_kernel<<<NBUCK, 256, 0, stream>>>(gcount, gbucket, adj, deg);
    cast_kernel<<<625, 256, 0, stream>>>(x, xb2);

    // layer 0: gather from xb2; gemm emits f32 out + bf16 copy into yb2
    gather_kernel<<<2500, 256, 0, stream>>>(xb2, adj, deg, aggb2);
    gemm_kernel<<<625, 256, 0, stream>>>(x, aggb2, Wl0, b0, Wr0, out, (u16*)yb2);

    // layer 1: gather from yb2; in-place on out
    gather_kernel<<<2500, 256, 0, stream>>>(yb2, adj, deg, aggb2);
    gemm_kernel<<<625, 256, 0, stream>>>(out, aggb2, Wl1, b1, Wr1, out, (u16*)0);
}

// Round 8
// 85.966 us; speedup vs baseline: 2.9978x; 1.4030x over previous
//
#include <hip/hip_runtime.h>

#define N_NODES 10000
#define N_EDGES 640000
#define D 128
#define MAXDEG 128
#define NBUCK 157            // ceil(10000 / 64) buckets of 64 dst nodes
#define BCAP 6144            // bucket capacity; mean 4076 -> huge margin
#define EPT 10               // edges/thread in pass1: 250 blocks * 256 * 10 = 640000

typedef unsigned int uint;
typedef unsigned short u16;
typedef short bf16x8 __attribute__((ext_vector_type(8)));
typedef float f32x4 __attribute__((ext_vector_type(4)));

__device__ __forceinline__ u16 f2bf(float f) {
    uint u = __float_as_uint(f);
    return (u16)((u + 0x7fffu + ((u >> 16) & 1u)) >> 16);   // round-nearest-even
}
__device__ __forceinline__ float bflo(uint v) { return __uint_as_float(v << 16); }
__device__ __forceinline__ float bfhi(uint v) { return __uint_as_float(v & 0xffff0000u); }

// ---------------------------------------------------------------------------
// Edge-index dtype probe (int64 vs int32). flag=1 -> int32.
__global__ void detect_kernel(const void* ei, int* flag) {
    const int* p = (const int*)ei;
    bool nz = false;
    for (int it = 0; it < 16; ++it) {
        int i = 2 * (threadIdx.x + it * 256) + 1;   // odd words in [1, 8191]
        if (p[i] != 0) nz = true;
    }
    if (__any(nz) && (threadIdx.x & 63) == 0) flag[0] = 1;
}

__device__ __forceinline__ int edge_at(const void* ei, int is32, int idx) {
    if (is32) return ((const int*)ei)[idx];
    return (int)((const long long*)ei)[idx];
}

// ---------------------------------------------------------------------------
// Pass 1: bin packed (dst<<16 | src) edges into NBUCK global bucket arrays.
__global__ __launch_bounds__(256)
void binp1_kernel(const void* __restrict__ ei, const int* __restrict__ flag,
                  int* __restrict__ gcount, uint* __restrict__ gbucket) {
    __shared__ int hist[NBUCK];
    __shared__ int base[NBUCK];
    const int t = threadIdx.x;
    if (t < NBUCK) hist[t] = 0;
    __syncthreads();
    const int is32 = *flag;
    const int e0 = blockIdx.x * (256 * EPT);
    uint pk[EPT];
    int  rk[EPT];
#pragma unroll
    for (int i = 0; i < EPT; ++i) {
        int e  = e0 + i * 256 + t;
        int s  = edge_at(ei, is32, e);
        int dn = edge_at(ei, is32, N_EDGES + e);
        pk[i] = ((uint)dn << 16) | (uint)s;
        rk[i] = atomicAdd(&hist[dn >> 6], 1);
    }
    __syncthreads();
    if (t < NBUCK) base[t] = atomicAdd(&gcount[t], hist[t]);
    __syncthreads();
#pragma unroll
    for (int i = 0; i < EPT; ++i) {
        int bkt = (int)(pk[i] >> 22);
        int pos = base[bkt] + rk[i];
        if (pos < BCAP) gbucket[(size_t)bkt * BCAP + pos] = pk[i];
    }
}

// ---------------------------------------------------------------------------
// Pass 2: one block per bucket; counting-sort into 64x128 u16 LDS tile,
// write adj rows coalesced (uint4) + per-node degree.
__global__ __launch_bounds__(256)
void binp2_kernel(const int* __restrict__ gcount, const uint* __restrict__ gbucket,
                  u16* __restrict__ adj, int* __restrict__ deg_g) {
    __shared__ __align__(16) u16 tile[64][MAXDEG];   // 16 KB
    __shared__ int cur[64];
    const int b = blockIdx.x;
    const int t = threadIdx.x;
    if (t < 64) cur[t] = 0;
    __syncthreads();
    const int total = min(gcount[b], BCAP);
    for (int e = t; e < total; e += 256) {
        uint pk = gbucket[(size_t)b * BCAP + e];
        int ln  = (int)((pk >> 16) & 63u);
        int src = (int)(pk & 0xffffu);
        int r = atomicAdd(&cur[ln], 1);
        if (r < MAXDEG) tile[ln][r] = (u16)src;
    }
    __syncthreads();
    const int node0 = b * 64;
    if (t < 64 && node0 + t < N_NODES) deg_g[node0 + t] = cur[t];
    const uint4* ts = (const uint4*)&tile[0][0];     // 1024 uint4, 16 per row
#pragma unroll
    for (int q = 0; q < 4; ++q) {
        int i = t + q * 256;
        int node = node0 + (i >> 4);
        if (node < N_NODES) ((uint4*)(adj + (size_t)node * MAXDEG))[i & 15] = ts[i];
    }
}

// ---------------------------------------------------------------------------
// f32 [N,D] -> packed bf16x2 [N,D/2]; 8 elems per thread
__global__ void cast_kernel(const float* __restrict__ in, uint* __restrict__ outb) {
    int t = blockIdx.x * 256 + threadIdx.x;
    if (t >= N_NODES * D / 8) return;
    const float4* p = (const float4*)in + (size_t)t * 2;
    float4 a = p[0], b = p[1];
    uint4 r;
    r.x = (uint)f2bf(a.x) | ((uint)f2bf(a.y) << 16);
    r.y = (uint)f2bf(a.z) | ((uint)f2bf(a.w) << 16);
    r.z = (uint)f2bf(b.x) | ((uint)f2bf(b.y) << 16);
    r.w = (uint)f2bf(b.z) | ((uint)f2bf(b.w) << 16);
    ((uint4*)outb)[t] = r;
}

// ---------------------------------------------------------------------------
// W prep: WT[layer][d][k] = bf16( k<128 ? Wl[k][d] : Wr[k-128][d] )
// 256 blocks: layer = b>>7, d = b&127; thread t = k.
__global__ __launch_bounds__(256)
void wprep_kernel(const float* __restrict__ Wl0, const float* __restrict__ Wr0,
                  const float* __restrict__ Wl1, const float* __restrict__ Wr1,
                  u16* __restrict__ WT0, u16* __restrict__ WT1) {
    const int b = blockIdx.x;
    const int layer = b >> 7, d = b & 127, k = threadIdx.x;
    const float* Wl = layer ? Wl1 : Wl0;
    const float* Wr = layer ? Wr1 : Wr0;
    u16* WT = layer ? WT1 : WT0;
    float v = (k < 128) ? Wl[k * D + d] : Wr[(k - 128) * D + d];
    WT[(size_t)d * 256 + k] = f2bf(v);
}

// ---------------------------------------------------------------------------
// Gather: one WAVE per node (2500 blocks x 4 waves); 16-neighbor batches with
// register prefetch of next adj words; 16 gather loads in flight.
__global__ __launch_bounds__(256)
void gather_kernel(const uint* __restrict__ xb2, const u16* __restrict__ adj,
                   const int* __restrict__ deg_g, uint* __restrict__ aggb2) {
    const int node = blockIdx.x * 4 + (threadIdx.x >> 6);
    const int lane = threadIdx.x & 63;
    const int dg = deg_g[node];
    const int cnt = min(dg, MAXDEG);
    const uint* __restrict__ rowu = (const uint*)(adj + (size_t)node * MAXDEG);
    float a0 = 0.f, a1 = 0.f;
    const int nb16 = cnt >> 4;
    if (nb16 > 0) {
        uint pkb[8];
#pragma unroll
        for (int i = 0; i < 8; ++i) pkb[i] = rowu[i];
        for (int b = 0; b < nb16; ++b) {
            uint cur[8];
#pragma unroll
            for (int i = 0; i < 8; ++i) cur[i] = pkb[i];
            if (b + 1 < nb16) {
#pragma unroll
                for (int i = 0; i < 8; ++i) pkb[i] = rowu[(b + 1) * 8 + i];
            }
            uint v[16];
#pragma unroll
            for (int i = 0; i < 8; ++i) {
                v[2 * i]     = xb2[(size_t)(cur[i] & 0xffffu) * 64 + lane];
                v[2 * i + 1] = xb2[(size_t)(cur[i] >> 16)     * 64 + lane];
            }
#pragma unroll
            for (int i = 0; i < 16; ++i) { a0 += bflo(v[i]); a1 += bfhi(v[i]); }
        }
    }
    for (int p = nb16 << 4; p < cnt; ++p) {
        uint v = xb2[(size_t)((const u16*)rowu)[p] * 64 + lane];
        a0 += bflo(v);
        a1 += bfhi(v);
    }
    float inv = 1.0f / fmaxf((float)dg, 1.0f);
    aggb2[(size_t)node * 64 + lane] = (uint)f2bf(a0 * inv) | ((uint)f2bf(a1 * inv) << 16);
}

// ---------------------------------------------------------------------------
// MFMA layer gemm: out[i,:] = ELU([agg|x] @ [Wl;Wr] + b), K=256, bf16 MFMA.
// 16 nodes/block (grid 625, exact), 256 thr = 4 waves; wave w owns cols
// [w*32, w*32+32) as two 16-col MFMA tiles. A staged in LDS (16B-XOR swizzle,
// same bijection on store and load). A/B frags share the k mapping
// k = kk*32 + (lane>>4)*8 + j, so any HW-internal k-permutation cancels.
__global__ __launch_bounds__(256)
void mfma_gemm_kernel(const uint* __restrict__ aggb2, const uint* __restrict__ xb2,
                      const u16* __restrict__ WT, const float* __restrict__ bias,
                      float* __restrict__ outf /* may be null */,
                      u16* __restrict__ outb /* may be null */) {
    __shared__ __align__(16) u16 A_lds[16 * 256];   // 8 KB: [row][k] bf16, swizzled
    const int t = threadIdx.x;
    const int nb = blockIdx.x * 16;
    {
        const int row = t >> 4, c = t & 15;          // coalesced 16B per lane
        const int node = nb + row;
        uint4 va = ((const uint4*)(aggb2 + (size_t)node * 64))[c];
        uint4 vx = ((const uint4*)(xb2  + (size_t)node * 64))[c];
        char* base = (char*)A_lds + row * 512;
        const int swz = (row & 7) << 4;
        *(uint4*)(base + ((c * 16) ^ swz))       = va;   // k 0..127   (agg)
        *(uint4*)(base + ((256 + c * 16) ^ swz)) = vx;   // k 128..255 (x)
    }
    __syncthreads();

    const int w = t >> 6, l = t & 63;
    const int lr = l & 15, g = l >> 4;
    f32x4 acc0 = {0.f, 0.f, 0.f, 0.f}, acc1 = {0.f, 0.f, 0.f, 0.f};
    const char* abase = (const char*)A_lds + lr * 512;
    const int aswz = (lr & 7) << 4;
    const u16* wt0 = WT + (size_t)(w * 32 + lr) * 256;        // col tile 0
    const u16* wt1 = WT + (size_t)(w * 32 + 16 + lr) * 256;   // col tile 1
#pragma unroll
    for (int kk = 0; kk < 8; ++kk) {
        bf16x8 af  = *(const bf16x8*)(abase + ((kk * 64 + g * 16) ^ aswz));
        bf16x8 bf0 = *(const bf16x8*)(wt0 + kk * 32 + g * 8);
        bf16x8 bf1 = *(const bf16x8*)(wt1 + kk * 32 + g * 8);
        acc0 = __builtin_amdgcn_mfma_f32_16x16x32_bf16(af, bf0, acc0, 0, 0, 0);
        acc1 = __builtin_amdgcn_mfma_f32_16x16x32_bf16(af, bf1, acc1, 0, 0, 0);
    }

    // epilogue: C/D layout col = lane&15, row = (lane>>4)*4 + reg  [HW-verified]
    const int col0 = w * 32 + lr, col1 = col0 + 16;
    const float b0v = bias[col0], b1v = bias[col1];
#pragma unroll
    for (int j = 0; j < 4; ++j) {
        const int node = nb + g * 4 + j;
        float v0 = acc0[j] + b0v; v0 = v0 > 0.f ? v0 : expm1f(v0);   // ELU
        float v1 = acc1[j] + b1v; v1 = v1 > 0.f ? v1 : expm1f(v1);
        if (outf) {
            outf[(size_t)node * D + col0] = v0;
            outf[(size_t)node * D + col1] = v1;
        }
        if (outb) {
            outb[(size_t)node * D + col0] = f2bf(v0);
            outb[(size_t)node * D + col1] = f2bf(v1);
        }
    }
}

// ---------------------------------------------------------------------------
extern "C" void kernel_launch(void* const* d_in, const int* in_sizes, int n_in,
                              void* d_out, int out_size, void* d_ws, size_t ws_size,
                              hipStream_t stream) {
    const float* x   = (const float*)d_in[0];
    const void*  ei  = d_in[1];
    const float* Wl0 = (const float*)d_in[2];
    const float* b0  = (const float*)d_in[3];
    const float* Wr0 = (const float*)d_in[4];
    const float* Wl1 = (const float*)d_in[5];
    const float* b1  = (const float*)d_in[6];
    const float* Wr1 = (const float*)d_in[7];
    float* out = (float*)d_out;

    char* ws = (char*)d_ws;
    // lifetime: gbucket dies after binp2; xb2/yb2 overlay its region.
    int*  flag    = (int*)(ws + 0);
    int*  gcount  = (int*)(ws + 1024);           // 628 B
    int*  deg     = (int*)(ws + 4096);           // 40 KB
    u16*  adj     = (u16*)(ws + 65536);          // 2.56 MB -> ends 2,625,536
    uint* gbucket = (uint*)(ws + 3145728);       // 3.86 MB -> ends 7,004,160
    uint* xb2     = (uint*)(ws + 3145728);       // 2.56 MB (after binp2)
    uint* yb2     = (uint*)(ws + 5767168);       // 2.56 MB -> ends 8,327,168
    uint* aggb2   = (uint*)(ws + 8388608);       // 2.56 MB -> ends 10,948,608
    u16*  WT0     = (u16*)(ws + 11010048);       // 64 KB
    u16*  WT1     = (u16*)(ws + 11075584);       // 64 KB -> ends 11,141,120

    hipMemsetAsync(ws, 0, 2048, stream);         // flag + gcount

    detect_kernel<<<1, 256, 0, stream>>>(ei, flag);
    binp1_kernel<<<250, 256, 0, stream>>>(ei, flag, gcount, gbucket);
    binp2_kernel<<<NBUCK, 256, 0, stream>>>(gcount, gbucket, adj, deg);
    cast_kernel<<<625, 256, 0, stream>>>(x, xb2);
    wprep_kernel<<<256, 256, 0, stream>>>(Wl0, Wr0, Wl1, Wr1, WT0, WT1);

    // layer 0: gather from xb2; gemm writes ONLY bf16 activations into yb2
    gather_kernel<<<2500, 256, 0, stream>>>(xb2, adj, deg, aggb2);
    mfma_gemm_kernel<<<625, 256, 0, stream>>>(aggb2, xb2, WT0, b0, (float*)0, (u16*)yb2);

    // layer 1: gather from yb2; gemm writes f32 final output
    gather_kernel<<<2500, 256, 0, stream>>>(yb2, adj, deg, aggb2);
    mfma_gemm_kernel<<<625, 256, 0, stream>>>(aggb2, yb2, WT1, b1, out, (u16*)0);
}

// Round 9
// 79.844 us; speedup vs baseline: 3.2276x; 1.0767x over previous
//
#include <hip/hip_runtime.h>

#define N_NODES 10000
#define N_EDGES 640000
#define D 128
#define MAXDEG 128
#define NBUCK 157            // ceil(10000 / 64) buckets of 64 dst nodes
#define BCAP 6144            // bucket capacity; mean 4076 -> huge margin
#define EPT 5                // edges/thread in pass1: 500 blocks * 256 * 5 = 640000
#define ZROW 10000           // zero-row index used for adj padding

typedef unsigned int uint;
typedef unsigned short u16;
typedef short bf16x8 __attribute__((ext_vector_type(8)));
typedef float f32x4 __attribute__((ext_vector_type(4)));

__device__ __forceinline__ u16 f2bf(float f) {
    uint u = __float_as_uint(f);
    return (u16)((u + 0x7fffu + ((u >> 16) & 1u)) >> 16);   // round-nearest-even
}
__device__ __forceinline__ float bflo(uint v) { return __uint_as_float(v << 16); }
__device__ __forceinline__ float bfhi(uint v) { return __uint_as_float(v & 0xffff0000u); }

__device__ __forceinline__ int edge_at(const void* ei, int is32, int idx) {
    if (is32) return ((const int*)ei)[idx];
    return (int)((const long long*)ei)[idx];
}

// ---------------------------------------------------------------------------
// Pass 1: bin packed (dst<<16 | src) edges into NBUCK global bucket arrays.
// Per-block dtype probe: int64 layout -> odd 32b words (high halves) all 0.
__global__ __launch_bounds__(256)
void binp1_kernel(const void* __restrict__ ei, int* __restrict__ gcount,
                  uint* __restrict__ gbucket) {
    __shared__ int hist[NBUCK];
    __shared__ int base[NBUCK];
    __shared__ int s_is32;
    const int t = threadIdx.x;
    if (t < NBUCK) hist[t] = 0;
    if (t == 0) s_is32 = 0;
    __syncthreads();
    const int e0 = blockIdx.x * (256 * EPT);
    if (((const int*)ei)[2 * (e0 + t) + 1] != 0) s_is32 = 1;   // benign race
    __syncthreads();
    const int is32 = s_is32;
    uint pk[EPT];
    int  rk[EPT];
#pragma unroll
    for (int i = 0; i < EPT; ++i) {
        int e  = e0 + i * 256 + t;
        int s  = edge_at(ei, is32, e);
        int dn = edge_at(ei, is32, N_EDGES + e);
        pk[i] = ((uint)dn << 16) | (uint)s;
        rk[i] = atomicAdd(&hist[dn >> 6], 1);
    }
    __syncthreads();
    if (t < NBUCK) base[t] = atomicAdd(&gcount[t], hist[t]);
    __syncthreads();
#pragma unroll
    for (int i = 0; i < EPT; ++i) {
        int bkt = (int)(pk[i] >> 22);
        int pos = base[bkt] + rk[i];
        if (pos < BCAP) gbucket[(size_t)bkt * BCAP + pos] = pk[i];
    }
}

// ---------------------------------------------------------------------------
// Fused prep: blocks [0,157) counting-sort buckets -> padded adj (pad=ZROW);
// [157,782) cast x -> packed bf16; [782,1038) build WT; 1038 zeroes xb2 ZROW.
__global__ __launch_bounds__(256)
void prep_kernel(const int* __restrict__ gcount, const uint* __restrict__ gbucket,
                 u16* __restrict__ adj, int* __restrict__ deg_g,
                 const float* __restrict__ x, uint* __restrict__ xb2,
                 const float* __restrict__ Wl0, const float* __restrict__ Wr0,
                 const float* __restrict__ Wl1, const float* __restrict__ Wr1,
                 u16* __restrict__ WT0, u16* __restrict__ WT1) {
    const int b = blockIdx.x;
    const int t = threadIdx.x;
    __shared__ __align__(16) u16 tile[64][MAXDEG];   // 16 KB
    __shared__ int cur[64];
    if (b < NBUCK) {
        uint* tw = (uint*)&tile[0][0];               // pad pattern = ZROW|ZROW
#pragma unroll
        for (int q = 0; q < 16; ++q) tw[t + q * 256] = ((uint)ZROW << 16) | ZROW;
        if (t < 64) cur[t] = 0;
        __syncthreads();
        const int total = min(gcount[b], BCAP);
        for (int e = t; e < total; e += 256) {
            uint pk = gbucket[(size_t)b * BCAP + e];
            int ln = (int)((pk >> 16) & 63u);
            int r = atomicAdd(&cur[ln], 1);
            if (r < MAXDEG) tile[ln][r] = (u16)(pk & 0xffffu);
        }
        __syncthreads();
        const int node0 = b * 64;
        if (t < 64 && node0 + t < N_NODES) deg_g[node0 + t] = cur[t];
        const uint4* ts = (const uint4*)&tile[0][0];
#pragma unroll
        for (int q = 0; q < 4; ++q) {
            int i = t + q * 256;
            int node = node0 + (i >> 4);
            if (node < N_NODES) ((uint4*)(adj + (size_t)node * MAXDEG))[i & 15] = ts[i];
        }
    } else if (b < NBUCK + 625) {
        int idx = (b - NBUCK) * 256 + t;             // 0..159999, exact
        const float4* p = (const float4*)x + (size_t)idx * 2;
        float4 a = p[0], bb = p[1];
        uint4 r;
        r.x = (uint)f2bf(a.x) | ((uint)f2bf(a.y) << 16);
        r.y = (uint)f2bf(a.z) | ((uint)f2bf(a.w) << 16);
        r.z = (uint)f2bf(bb.x) | ((uint)f2bf(bb.y) << 16);
        r.w = (uint)f2bf(bb.z) | ((uint)f2bf(bb.w) << 16);
        ((uint4*)xb2)[idx] = r;
    } else if (b < NBUCK + 625 + 256) {
        int b2 = b - (NBUCK + 625);
        int layer = b2 >> 7, d = b2 & 127, k = t;
        const float* Wl = layer ? Wl1 : Wl0;
        const float* Wr = layer ? Wr1 : Wr0;
        u16* WT = layer ? WT1 : WT0;
        float v = (k < 128) ? Wl[k * D + d] : Wr[(k - 128) * D + d];
        WT[(size_t)d * 256 + k] = f2bf(v);
    } else {
        if (t < 16) ((uint4*)(xb2 + (size_t)ZROW * 64))[t] = make_uint4(0, 0, 0, 0);
    }
}

// ---------------------------------------------------------------------------
// Gather v2: one WAVE per node. Lane (g=l>>4, c=l&15): per 16-edge chunk,
// 4 x uint4 gather loads (1 KB/wave-instr, 4 edges each) + 2 uniform uint4
// adj reads; padding ids hit the zero row. Final shfl_xor(16/32) reduction.
__global__ __launch_bounds__(256)
void gather_kernel(const uint* __restrict__ xb2, const u16* __restrict__ adj,
                   const int* __restrict__ deg_g, uint* __restrict__ aggb2) {
    const int node = blockIdx.x * 4 + (threadIdx.x >> 6);
    const int l = threadIdx.x & 63;
    const int g = l >> 4;          // edge slot 0..3
    const int c = l & 15;          // 16B column chunk
    const int half = g >> 1;
    const int sh = (g & 1) << 4;
    const int dg = deg_g[node];
    const int cnt = min(dg, MAXDEG);
    const uint4* __restrict__ rowq = (const uint4*)(adj + (size_t)node * MAXDEG);
    float acc[8];
#pragma unroll
    for (int i = 0; i < 8; ++i) acc[i] = 0.f;
    const int nch = (cnt + 15) >> 4;
#pragma unroll 2
    for (int ch = 0; ch < nch; ++ch) {
        uint4 wa = rowq[2 * ch];
        uint4 wb = rowq[2 * ch + 1];
        uint a0 = half ? wa.y : wa.x;        // u16 idx g       (edge ch*16+g)
        uint a1 = half ? wa.w : wa.z;        // u16 idx 4+g
        uint b0 = half ? wb.y : wb.x;        // u16 idx 8+g
        uint b1 = half ? wb.w : wb.z;        // u16 idx 12+g
        uint id0 = (a0 >> sh) & 0xffffu;
        uint id1 = (a1 >> sh) & 0xffffu;
        uint id2 = (b0 >> sh) & 0xffffu;
        uint id3 = (b1 >> sh) & 0xffffu;
        uint4 v0 = ((const uint4*)(xb2 + (size_t)id0 * 64))[c];
        uint4 v1 = ((const uint4*)(xb2 + (size_t)id1 * 64))[c];
        uint4 v2 = ((const uint4*)(xb2 + (size_t)id2 * 64))[c];
        uint4 v3 = ((const uint4*)(xb2 + (size_t)id3 * 64))[c];
        acc[0] += bflo(v0.x) + bflo(v1.x) + bflo(v2.x) + bflo(v3.x);
        acc[1] += bfhi(v0.x) + bfhi(v1.x) + bfhi(v2.x) + bfhi(v3.x);
        acc[2] += bflo(v0.y) + bflo(v1.y) + bflo(v2.y) + bflo(v3.y);
        acc[3] += bfhi(v0.y) + bfhi(v1.y) + bfhi(v2.y) + bfhi(v3.y);
        acc[4] += bflo(v0.z) + bflo(v1.z) + bflo(v2.z) + bflo(v3.z);
        acc[5] += bfhi(v0.z) + bfhi(v1.z) + bfhi(v2.z) + bfhi(v3.z);
        acc[6] += bflo(v0.w) + bflo(v1.w) + bflo(v2.w) + bflo(v3.w);
        acc[7] += bfhi(v0.w) + bfhi(v1.w) + bfhi(v2.w) + bfhi(v3.w);
    }
#pragma unroll
    for (int i = 0; i < 8; ++i) {
        float r = acc[i];
        r += __shfl_xor(r, 16, 64);
        r += __shfl_xor(r, 32, 64);
        acc[i] = r;
    }
    if (g == 0) {
        float inv = 1.0f / fmaxf((float)dg, 1.0f);
        uint4 o;
        o.x = (uint)f2bf(acc[0] * inv) | ((uint)f2bf(acc[1] * inv) << 16);
        o.y = (uint)f2bf(acc[2] * inv) | ((uint)f2bf(acc[3] * inv) << 16);
        o.z = (uint)f2bf(acc[4] * inv) | ((uint)f2bf(acc[5] * inv) << 16);
        o.w = (uint)f2bf(acc[6] * inv) | ((uint)f2bf(acc[7] * inv) << 16);
        ((uint4*)(aggb2 + (size_t)node * 64))[c] = o;
    }
}

// ---------------------------------------------------------------------------
// MFMA layer gemm: out[i,:] = ELU([agg|x] @ [Wl;Wr] + b), K=256, bf16 MFMA.
// 16 nodes/block (grid 625), 4 waves; wave w owns cols [w*32, w*32+32).
// A staged in LDS with 16B-XOR swizzle (same bijection store & load);
// A/B frags share k mapping k = kk*32 + (lane>>4)*8 + j -> permutation cancels.
__global__ __launch_bounds__(256)
void mfma_gemm_kernel(const uint* __restrict__ aggb2, const uint* __restrict__ xb2,
                      const u16* __restrict__ WT, const float* __restrict__ bias,
                      float* __restrict__ outf /* may be null */,
                      u16* __restrict__ outb /* may be null */) {
    __shared__ __align__(16) u16 A_lds[16 * 256];   // 8 KB
    const int t = threadIdx.x;
    const int nb = blockIdx.x * 16;
    {
        const int row = t >> 4, c = t & 15;
        const int node = nb + row;
        uint4 va = ((const uint4*)(aggb2 + (size_t)node * 64))[c];
        uint4 vx = ((const uint4*)(xb2  + (size_t)node * 64))[c];
        char* base = (char*)A_lds + row * 512;
        const int swz = (row & 7) << 4;
        *(uint4*)(base + ((c * 16) ^ swz))       = va;   // k 0..127   (agg)
        *(uint4*)(base + ((256 + c * 16) ^ swz)) = vx;   // k 128..255 (x)
    }
    __syncthreads();

    const int w = t >> 6, l = t & 63;
    const int lr = l & 15, g = l >> 4;
    f32x4 acc0 = {0.f, 0.f, 0.f, 0.f}, acc1 = {0.f, 0.f, 0.f, 0.f};
    const char* abase = (const char*)A_lds + lr * 512;
    const int aswz = (lr & 7) << 4;
    const u16* wt0 = WT + (size_t)(w * 32 + lr) * 256;
    const u16* wt1 = WT + (size_t)(w * 32 + 16 + lr) * 256;
#pragma unroll
    for (int kk = 0; kk < 8; ++kk) {
        bf16x8 af  = *(const bf16x8*)(abase + ((kk * 64 + g * 16) ^ aswz));
        bf16x8 bf0 = *(const bf16x8*)(wt0 + kk * 32 + g * 8);
        bf16x8 bf1 = *(const bf16x8*)(wt1 + kk * 32 + g * 8);
        acc0 = __builtin_amdgcn_mfma_f32_16x16x32_bf16(af, bf0, acc0, 0, 0, 0);
        acc1 = __builtin_amdgcn_mfma_f32_16x16x32_bf16(af, bf1, acc1, 0, 0, 0);
    }

    // C/D layout: col = lane&15, row = (lane>>4)*4 + reg  [HW-verified]
    const int col0 = w * 32 + lr, col1 = col0 + 16;
    const float b0v = bias[col0], b1v = bias[col1];
#pragma unroll
    for (int j = 0; j < 4; ++j) {
        const int node = nb + g * 4 + j;
        float v0 = acc0[j] + b0v; v0 = v0 > 0.f ? v0 : expm1f(v0);   // ELU
        float v1 = acc1[j] + b1v; v1 = v1 > 0.f ? v1 : expm1f(v1);
        if (outf) {
            outf[(size_t)node * D + col0] = v0;
            outf[(size_t)node * D + col1] = v1;
        }
        if (outb) {
            outb[(size_t)node * D + col0] = f2bf(v0);
            outb[(size_t)node * D + col1] = f2bf(v1);
        }
    }
    // layer 0 also zeroes the next layer's gather zero-row (after prep, before gather1)
    if (outb && blockIdx.x == 0 && t < 16)
        ((uint4*)(outb + (size_t)ZROW * D))[t] = make_uint4(0, 0, 0, 0);
}

// ---------------------------------------------------------------------------
extern "C" void kernel_launch(void* const* d_in, const int* in_sizes, int n_in,
                              void* d_out, int out_size, void* d_ws, size_t ws_size,
                              hipStream_t stream) {
    const float* x   = (const float*)d_in[0];
    const void*  ei  = d_in[1];
    const float* Wl0 = (const float*)d_in[2];
    const float* b0  = (const float*)d_in[3];
    const float* Wr0 = (const float*)d_in[4];
    const float* Wl1 = (const float*)d_in[5];
    const float* b1  = (const float*)d_in[6];
    const float* Wr1 = (const float*)d_in[7];
    float* out = (float*)d_out;

    char* ws = (char*)d_ws;
    // Overlay plan: gbucket [3,145,728 .. 7,004,160) is dead after prep.
    // yb2 + aggb2 overlay it (first written after prep). xb2 and WT must NOT
    // overlay it (written during prep, while binp2-blocks still read gbucket).
    int*  gcount  = (int*)(ws + 1024);           // 628 B
    int*  deg     = (int*)(ws + 4096);           // 40 KB
    u16*  adj     = (u16*)(ws + 65536);          // 2.56 MB  -> 2,625,536
    uint* gbucket = (uint*)(ws + 3145728);       // 3.86 MB  -> 7,004,160
    uint* yb2     = (uint*)(ws + 3145728);       // 2.56 MB + zrow (overlay)
    uint* aggb2   = (uint*)(ws + 5705984);       // 2.56 MB (overlay) -> 8,265,984
    uint* xb2     = (uint*)(ws + 8266240);       // 2.56 MB + zrow -> 10,826,496
    u16*  WT0     = (u16*)(ws + 10826752);       // 64 KB
    u16*  WT1     = (u16*)(ws + 10892288);       // 64 KB -> ends 10,957,824

    hipMemsetAsync(ws, 0, 4096, stream);         // gcount

    binp1_kernel<<<500, 256, 0, stream>>>(ei, gcount, gbucket);
    prep_kernel<<<NBUCK + 625 + 256 + 1, 256, 0, stream>>>(
        gcount, gbucket, adj, deg, x, xb2, Wl0, Wr0, Wl1, Wr1, WT0, WT1);

    // layer 0: gather from xb2; gemm writes bf16 activations into yb2 (+zrow)
    gather_kernel<<<2500, 256, 0, stream>>>(xb2, adj, deg, aggb2);
    mfma_gemm_kernel<<<625, 256, 0, stream>>>(aggb2, xb2, WT0, b0, (float*)0, (u16*)yb2);

    // layer 1: gather from yb2; gemm writes f32 final output
    gather_kernel<<<2500, 256, 0, stream>>>(yb2, adj, deg, aggb2);
    mfma_gemm_kernel<<<625, 256, 0, stream>>>(aggb2, yb2, WT1, b1, out, (u16*)0);
}